// Round 5
// baseline (416.847 us; speedup 1.0000x reference)
//
#include <hip/hip_runtime.h>

// GCN: 3 layers, dims 64->64->64->32, N=100000 nodes, E=1600000 edges.
// Round 5:
//  - byte-packed histogram (4 nodes/word): R4 evidence = k_hist 67us, 56MB
//    WRITE for a 400KB cnt array (atomic line-flush amplification). Packing
//    4x counters/line lets the coherence point coalesce.
//  - dis[src] pre-folded into h rows at GEMM epilogue (aggregation is linear):
//    CSR payload = bare 4B src index; aggregate inner loop is pure adds.
//  - dis computed in scan_final (one fewer dispatch).
// Max indegree ~40 (Poisson(16) over 100k nodes) -> 8-bit counters safe.

static inline int cdiv(int a, int b) { return (a + b - 1) / b; }

__global__ void k_zero_int(unsigned* p, int n) {
    int i = blockIdx.x * blockDim.x + threadIdx.x;
    if (i < n) p[i] = 0u;
}

// byte-packed histogram of dst; rank = previous byte value (arrival order)
__global__ void k_hist(const int* __restrict__ dst, unsigned* __restrict__ cnt_p,
                       int* __restrict__ rank, int E) {
    int i = blockIdx.x * blockDim.x + threadIdx.x;
    if (i >= E) return;
    int d = dst[i];
    int sh = (d & 3) * 8;
    unsigned ret = atomicAdd(&cnt_p[d >> 2], 1u << sh);
    rank[i] = (int)((ret >> sh) & 0xffu);
}

// ---- hierarchical exclusive scan over byte-packed counts ----
// each thread owns one packed word = 4 nodes; 256 threads/block = 1024 nodes.

__global__ void k_scan_partial(const unsigned* __restrict__ cnt_p,
                               int* __restrict__ bsum, int nw) {
    __shared__ int red[256];
    int t = threadIdx.x, b = blockIdx.x;
    int wi = b * 256 + t;
    unsigned w = (wi < nw) ? cnt_p[wi] : 0u;
    int s = (int)((w & 0xffu) + ((w >> 8) & 0xffu) + ((w >> 16) & 0xffu) + (w >> 24));
    red[t] = s;
    __syncthreads();
    for (int off = 128; off > 0; off >>= 1) {
        if (t < off) red[t] += red[t + off];
        __syncthreads();
    }
    if (t == 0) bsum[b] = red[0];
}

__global__ void k_scan_bsum(int* bsum, int nb) {
    __shared__ int sh[1024];
    int t = threadIdx.x;
    int v = (t < nb) ? bsum[t] : 0;
    sh[t] = v;
    __syncthreads();
    for (int off = 1; off < 1024; off <<= 1) {
        int u = (t >= off) ? sh[t - off] : 0;
        __syncthreads();
        sh[t] += u;
        __syncthreads();
    }
    if (t < nb) bsum[t] = sh[t] - v;  // exclusive
}

// writes row_start[0..n] AND dis[0..n)
__global__ void k_scan_final(const unsigned* __restrict__ cnt_p, const int* __restrict__ bsum,
                             int* __restrict__ row_start, float* __restrict__ dis, int n) {
    __shared__ int sh[256];
    int t = threadIdx.x, b = blockIdx.x;
    int wi = b * 256 + t;
    int nw = (n + 3) >> 2;
    unsigned w = (wi < nw) ? cnt_p[wi] : 0u;
    int v[4];
    v[0] = (int)(w & 0xffu);
    v[1] = (int)((w >> 8) & 0xffu);
    v[2] = (int)((w >> 16) & 0xffu);
    v[3] = (int)(w >> 24);
    int s = v[0] + v[1] + v[2] + v[3];
    sh[t] = s;
    __syncthreads();
    for (int off = 1; off < 256; off <<= 1) {
        int u = (t >= off) ? sh[t - off] : 0;
        __syncthreads();
        sh[t] += u;
        __syncthreads();
    }
    int run = sh[t] - s + bsum[b];  // exclusive prefix for this word
    int i0 = wi * 4;
#pragma unroll
    for (int j = 0; j < 4; ++j) {
        int i = i0 + j;
        if (i < n) {
            row_start[i] = run;
            dis[i] = rsqrtf(1.0f + (float)v[j]);
            run += v[j];
            if (i == n - 1) row_start[n] = run;
        }
    }
}

// atomic-free CSR fill: bare src index, position from precomputed rank
__global__ void k_fill(const int* __restrict__ src, const int* __restrict__ dst,
                       const int* __restrict__ rank, const int* __restrict__ row_start,
                       int* __restrict__ csr_src, int E) {
    int e = blockIdx.x * blockDim.x + threadIdx.x;
    if (e >= E) return;
    csr_src[row_start[dst[e]] + rank[e]] = src[e];
}

// H[n x M] = (X[n x K] @ W[K x M]) * dis[row]; 8 outputs/thread.
template <int K, int M>
__global__ void k_gemm(const float* __restrict__ X, const float* __restrict__ W,
                       const float* __restrict__ dis, float* __restrict__ H, int n) {
    constexpr int CPT = 8;
    constexpr int TPR = M / CPT;
    constexpr int ROWS = 256 / TPR;
    constexpr int KP = K + 1;
    __shared__ float Ws[K * M];
    __shared__ float Xs[ROWS * KP];
    int tid = threadIdx.x;
    for (int idx = tid; idx < K * M / 4; idx += 256)
        ((float4*)Ws)[idx] = ((const float4*)W)[idx];
    int row0 = blockIdx.x * ROWS;
    for (int idx = tid; idx < ROWS * (K / 4); idx += 256) {
        int r = idx / (K / 4), kq = idx % (K / 4);
        int row = row0 + r;
        float4 vv = (row < n) ? ((const float4*)X)[(size_t)row * (K / 4) + kq]
                              : make_float4(0.f, 0.f, 0.f, 0.f);
        Xs[r * KP + kq * 4 + 0] = vv.x;
        Xs[r * KP + kq * 4 + 1] = vv.y;
        Xs[r * KP + kq * 4 + 2] = vv.z;
        Xs[r * KP + kq * 4 + 3] = vv.w;
    }
    __syncthreads();
    int r = tid / TPR, c0 = (tid % TPR) * CPT;
    int row = row0 + r;
    if (row >= n) return;
    float4 a0 = make_float4(0.f, 0.f, 0.f, 0.f);
    float4 a1 = make_float4(0.f, 0.f, 0.f, 0.f);
#pragma unroll
    for (int k = 0; k < K; ++k) {
        float xv = Xs[r * KP + k];
        float4 w0 = ((const float4*)Ws)[(k * M + c0) / 4];
        float4 w1 = ((const float4*)Ws)[(k * M + c0) / 4 + 1];
        a0.x = fmaf(xv, w0.x, a0.x);
        a0.y = fmaf(xv, w0.y, a0.y);
        a0.z = fmaf(xv, w0.z, a0.z);
        a0.w = fmaf(xv, w0.w, a0.w);
        a1.x = fmaf(xv, w1.x, a1.x);
        a1.y = fmaf(xv, w1.y, a1.y);
        a1.z = fmaf(xv, w1.z, a1.z);
        a1.w = fmaf(xv, w1.w, a1.w);
    }
    float dn = dis[row];
    a0.x *= dn; a0.y *= dn; a0.z *= dn; a0.w *= dn;
    a1.x *= dn; a1.y *= dn; a1.z *= dn; a1.w *= dn;
    ((float4*)H)[(size_t)row * (M / 4) + c0 / 4] = a0;
    ((float4*)H)[(size_t)row * (M / 4) + c0 / 4 + 1] = a1;
}

// fused aggregate over pre-scaled h': one WAVE per node, pure float4 adds.
// out[i] = dis[i]*(sum_{e} h'[src] + h'[i]) + b
template <int M, bool RELU>
__global__ void k_aggregate(const float* __restrict__ h, const float* __restrict__ dis,
                            const int* __restrict__ row_start, const int* __restrict__ csr_src,
                            const float* __restrict__ b, float* __restrict__ out, int n) {
    constexpr int G = M / 4;   // float4 groups per node row
    constexpr int S = 64 / G;  // edge slots per wave
    int gtid = blockIdx.x * blockDim.x + threadIdx.x;
    int node = gtid >> 6;
    if (node >= n) return;
    int lane = threadIdx.x & 63;
    int fg = lane % G;
    int slot = lane / G;
    int e1 = row_start[node + 1];
    const float4* h4 = (const float4*)h;
    float4 acc = make_float4(0.f, 0.f, 0.f, 0.f);
    int e = row_start[node] + slot;
    for (; e + S < e1; e += 2 * S) {
        int s0 = csr_src[e];
        int s1 = csr_src[e + S];
        float4 v0 = h4[(size_t)s0 * G + fg];
        float4 v1 = h4[(size_t)s1 * G + fg];
        acc.x += v0.x + v1.x;
        acc.y += v0.y + v1.y;
        acc.z += v0.z + v1.z;
        acc.w += v0.w + v1.w;
    }
    if (e < e1) {
        int s0 = csr_src[e];
        float4 v0 = h4[(size_t)s0 * G + fg];
        acc.x += v0.x;
        acc.y += v0.y;
        acc.z += v0.z;
        acc.w += v0.w;
    }
#pragma unroll
    for (int off = G; off < 64; off <<= 1) {
        acc.x += __shfl_xor(acc.x, off, 64);
        acc.y += __shfl_xor(acc.y, off, 64);
        acc.z += __shfl_xor(acc.z, off, 64);
        acc.w += __shfl_xor(acc.w, off, 64);
    }
    if (slot == 0) {
        float dn = dis[node];
        float4 hv = h4[(size_t)node * G + fg];
        float4 bb = ((const float4*)b)[fg];
        float4 r;
        r.x = (acc.x + hv.x) * dn + bb.x;
        r.y = (acc.y + hv.y) * dn + bb.y;
        r.z = (acc.z + hv.z) * dn + bb.z;
        r.w = (acc.w + hv.w) * dn + bb.w;
        if (RELU) {
            r.x = fmaxf(r.x, 0.f);
            r.y = fmaxf(r.y, 0.f);
            r.z = fmaxf(r.z, 0.f);
            r.w = fmaxf(r.w, 0.f);
        }
        ((float4*)out)[(size_t)node * G + fg] = r;
    }
}

extern "C" void kernel_launch(void* const* d_in, const int* in_sizes, int n_in,
                              void* d_out, int out_size, void* d_ws, size_t ws_size,
                              hipStream_t stream) {
    const float* x   = (const float*)d_in[0];
    const int*   ei  = (const int*)d_in[1];
    const float* W1  = (const float*)d_in[2];
    const float* b1  = (const float*)d_in[3];
    const float* W2  = (const float*)d_in[4];
    const float* b2  = (const float*)d_in[5];
    const float* W3  = (const float*)d_in[6];
    const float* b3  = (const float*)d_in[7];
    float* out = (float*)d_out;

    const int N = in_sizes[0] / 64;
    const int E = in_sizes[1] / 2;
    const int* src = ei;
    const int* dst = ei + E;

    // workspace layout
    const size_t Np = (size_t)((N + 63) / 64) * 64;
    const int Npw = (int)(Np / 4);  // packed counter words
    char* p = (char*)d_ws;
    unsigned* cnt_p  = (unsigned*)p; p += Np * sizeof(unsigned);  // only Npw used
    int*   row_start = (int*)p;   p += (Np + 64) * sizeof(int);
    int*   bsum      = (int*)p;   p += 1024 * sizeof(int);
    float* dis       = (float*)p; p += Np * sizeof(float);
    int*   rank      = (int*)p;   p += (size_t)E * sizeof(int);
    int*   csr_src   = (int*)p;   p += (size_t)E * sizeof(int);
    float* bufH      = (float*)p; p += Np * 64 * sizeof(float);
    float* bufX      = (float*)p; p += Np * 64 * sizeof(float);
    (void)ws_size;

    const int B = 256;
    const int nw = (N + 3) / 4;          // packed words in use
    const int nb = cdiv(nw, 256);        // scan blocks (98)

    // ---- CSR build ----
    k_zero_int<<<cdiv(Npw, B), B, 0, stream>>>(cnt_p, Npw);
    k_hist<<<cdiv(E, B), B, 0, stream>>>(dst, cnt_p, rank, E);
    k_scan_partial<<<nb, B, 0, stream>>>(cnt_p, bsum, nw);
    k_scan_bsum<<<1, 1024, 0, stream>>>(bsum, nb);
    k_scan_final<<<nb, B, 0, stream>>>(cnt_p, bsum, row_start, dis, N);
    k_fill<<<cdiv(E, B), B, 0, stream>>>(src, dst, rank, row_start, csr_src, E);

    // ---- layer 1: x(64) -> 64, relu ----
    k_gemm<64, 64><<<cdiv(N, 32), B, 0, stream>>>(x, W1, dis, bufH, N);
    k_aggregate<64, true><<<cdiv(N * 64, B), B, 0, stream>>>(
        bufH, dis, row_start, csr_src, b1, bufX, N);

    // ---- layer 2: 64 -> 64, relu ----
    k_gemm<64, 64><<<cdiv(N, 32), B, 0, stream>>>(bufX, W2, dis, bufH, N);
    k_aggregate<64, true><<<cdiv(N * 64, B), B, 0, stream>>>(
        bufH, dis, row_start, csr_src, b2, bufX, N);

    // ---- layer 3: 64 -> 32, no relu ----
    k_gemm<64, 32><<<cdiv(N, 64), B, 0, stream>>>(bufX, W3, dis, bufH, N);
    k_aggregate<32, false><<<cdiv(N * 64, B), B, 0, stream>>>(
        bufH, dis, row_start, csr_src, b3, out, N);
}

// Round 6
// 399.862 us; speedup vs baseline: 1.0425x; 1.0425x over previous
//
#include <hip/hip_runtime.h>

// GCN: 3 layers, dims 64->64->64->32, N=100000 nodes, E=1600000 edges.
// Round 6: CSR build via LDS two-level counting sort -- ZERO global atomics.
// R5 evidence: global-atomic hist is per-op bound (~24G atomics/s, 56MB line
// flush regardless of counter packing; packing even regressed via intra-word
// contention). So: bucket by dst>>8 with LDS hists + hierarchical scan +
// LDS-cursor scatter (pass A), then per-bucket LDS counting sort emitting
// csr_src/row_start/dis (pass B).
// dis[src] stays folded into h at GEMM epilogue (R5); aggregate = pure adds.

static inline int cdiv(int a, int b) { return (a + b - 1) / b; }

#define ACHUNK 4096   // edges per pass-A block (256 thr x 16)
#define MAXNBK 512    // max buckets (N <= 131072)

// ---- pass A1: per-block bucket histogram -> counts_t[bucket*NBA + block]
__global__ void k_bucket_hist(const int* __restrict__ dst, int* __restrict__ counts_t,
                              int NBK, int NBA, int E) {
    __shared__ int cnt[MAXNBK];
    int t = threadIdx.x, b = blockIdx.x;
    for (int i = t; i < NBK; i += 256) cnt[i] = 0;
    __syncthreads();
    int e0 = b * ACHUNK;
#pragma unroll
    for (int j = 0; j < ACHUNK / 256; ++j) {
        int e = e0 + j * 256 + t;
        if (e < E) atomicAdd(&cnt[dst[e] >> 8], 1);
    }
    __syncthreads();
    for (int i = t; i < NBK; i += 256) counts_t[i * NBA + b] = cnt[i];
}

// ---- hierarchical exclusive scan over plain int array a[0..n) -> out[0..n)
#define SCAN_T 256
#define SCAN_V 4
#define SCAN_CHUNK 1024

__global__ void k_scan_partial(const int* __restrict__ a, int* __restrict__ bsum, int n) {
    __shared__ int red[SCAN_T];
    int t = threadIdx.x, b = blockIdx.x;
    int base = b * SCAN_CHUNK + t * SCAN_V;
    int s = 0;
#pragma unroll
    for (int j = 0; j < SCAN_V; ++j) { int i = base + j; if (i < n) s += a[i]; }
    red[t] = s;
    __syncthreads();
    for (int off = SCAN_T / 2; off > 0; off >>= 1) {
        if (t < off) red[t] += red[t + off];
        __syncthreads();
    }
    if (t == 0) bsum[b] = red[0];
}

__global__ void k_scan_bsum(int* bsum, int nb) {
    __shared__ int sh[1024];
    int t = threadIdx.x;
    int v = (t < nb) ? bsum[t] : 0;
    sh[t] = v;
    __syncthreads();
    for (int off = 1; off < 1024; off <<= 1) {
        int u = (t >= off) ? sh[t - off] : 0;
        __syncthreads();
        sh[t] += u;
        __syncthreads();
    }
    if (t < nb) bsum[t] = sh[t] - v;  // exclusive
}

__global__ void k_scan_final(const int* __restrict__ a, const int* __restrict__ bsum,
                             int* __restrict__ out, int n) {
    __shared__ int sh[SCAN_T];
    int t = threadIdx.x, b = blockIdx.x;
    int base = b * SCAN_CHUNK + t * SCAN_V;
    int v[SCAN_V];
    int s = 0;
#pragma unroll
    for (int j = 0; j < SCAN_V; ++j) {
        int i = base + j;
        v[j] = (i < n) ? a[i] : 0;
        s += v[j];
    }
    sh[t] = s;
    __syncthreads();
    for (int off = 1; off < SCAN_T; off <<= 1) {
        int u = (t >= off) ? sh[t - off] : 0;
        __syncthreads();
        sh[t] += u;
        __syncthreads();
    }
    int run = sh[t] - s + bsum[b];
#pragma unroll
    for (int j = 0; j < SCAN_V; ++j) {
        int i = base + j;
        if (i < n) { out[i] = run; run += v[j]; }
    }
}

// ---- pass A3: scatter edges into bucket regions via LDS cursors.
// packed word: src (24 bits) | (dst & 255) << 24. src < 2^17 fits.
__global__ void k_bucket_scatter(const int* __restrict__ src, const int* __restrict__ dst,
                                 const int* __restrict__ offsets, unsigned* __restrict__ bucketed,
                                 int NBK, int NBA, int E) {
    __shared__ int curs[MAXNBK];
    int t = threadIdx.x, b = blockIdx.x;
    for (int i = t; i < NBK; i += 256) curs[i] = offsets[i * NBA + b];
    __syncthreads();
    int e0 = b * ACHUNK;
#pragma unroll
    for (int j = 0; j < ACHUNK / 256; ++j) {
        int e = e0 + j * 256 + t;
        if (e < E) {
            int d = dst[e];
            int pos = atomicAdd(&curs[d >> 8], 1);
            bucketed[pos] = (unsigned)src[e] | ((unsigned)(d & 255) << 24);
        }
    }
}

// ---- pass B: one block per bucket. LDS hist over 256 nodes -> LDS scan ->
// emit csr_src (dst-sorted), row_start, dis.
__global__ void k_bucket_build(const unsigned* __restrict__ bucketed,
                               const int* __restrict__ offsets,
                               int* __restrict__ csr_src, int* __restrict__ row_start,
                               float* __restrict__ dis, int NBK, int NBA, int N, int E) {
    __shared__ int cnt[256];
    __shared__ int sc[256];
    int t = threadIdx.x, k = blockIdx.x;
    int base = offsets[k * NBA];
    int end = (k + 1 < NBK) ? offsets[(k + 1) * NBA] : E;
    cnt[t] = 0;
    __syncthreads();
    for (int i = base + t; i < end; i += 256)
        atomicAdd(&cnt[bucketed[i] >> 24], 1);
    __syncthreads();
    int c = cnt[t];
    sc[t] = c;
    __syncthreads();
    for (int off = 1; off < 256; off <<= 1) {
        int u = (t >= off) ? sc[t - off] : 0;
        __syncthreads();
        sc[t] += u;
        __syncthreads();
    }
    int excl = sc[t] - c;
    int node = k * 256 + t;
    if (node < N) {
        row_start[node] = base + excl;
        dis[node] = rsqrtf(1.0f + (float)c);
    }
    if (k == 0 && t == 0) row_start[N] = E;
    cnt[t] = base + excl;  // reuse as cursor
    __syncthreads();
    for (int i = base + t; i < end; i += 256) {
        unsigned w = bucketed[i];
        int pos = atomicAdd(&cnt[w >> 24], 1);
        csr_src[pos] = (int)(w & 0xFFFFFFu);
    }
}

// ---- H[n x M] = (X[n x K] @ W[K x M]) * dis[row]; 8 outputs/thread.
template <int K, int M>
__global__ void k_gemm(const float* __restrict__ X, const float* __restrict__ W,
                       const float* __restrict__ dis, float* __restrict__ H, int n) {
    constexpr int CPT = 8;
    constexpr int TPR = M / CPT;
    constexpr int ROWS = 256 / TPR;
    constexpr int KP = K + 1;
    __shared__ float Ws[K * M];
    __shared__ float Xs[ROWS * KP];
    int tid = threadIdx.x;
    for (int idx = tid; idx < K * M / 4; idx += 256)
        ((float4*)Ws)[idx] = ((const float4*)W)[idx];
    int row0 = blockIdx.x * ROWS;
    for (int idx = tid; idx < ROWS * (K / 4); idx += 256) {
        int r = idx / (K / 4), kq = idx % (K / 4);
        int row = row0 + r;
        float4 vv = (row < n) ? ((const float4*)X)[(size_t)row * (K / 4) + kq]
                              : make_float4(0.f, 0.f, 0.f, 0.f);
        Xs[r * KP + kq * 4 + 0] = vv.x;
        Xs[r * KP + kq * 4 + 1] = vv.y;
        Xs[r * KP + kq * 4 + 2] = vv.z;
        Xs[r * KP + kq * 4 + 3] = vv.w;
    }
    __syncthreads();
    int r = tid / TPR, c0 = (tid % TPR) * CPT;
    int row = row0 + r;
    if (row >= n) return;
    float4 a0 = make_float4(0.f, 0.f, 0.f, 0.f);
    float4 a1 = make_float4(0.f, 0.f, 0.f, 0.f);
#pragma unroll
    for (int k = 0; k < K; ++k) {
        float xv = Xs[r * KP + k];
        float4 w0 = ((const float4*)Ws)[(k * M + c0) / 4];
        float4 w1 = ((const float4*)Ws)[(k * M + c0) / 4 + 1];
        a0.x = fmaf(xv, w0.x, a0.x);
        a0.y = fmaf(xv, w0.y, a0.y);
        a0.z = fmaf(xv, w0.z, a0.z);
        a0.w = fmaf(xv, w0.w, a0.w);
        a1.x = fmaf(xv, w1.x, a1.x);
        a1.y = fmaf(xv, w1.y, a1.y);
        a1.z = fmaf(xv, w1.z, a1.z);
        a1.w = fmaf(xv, w1.w, a1.w);
    }
    float dn = dis[row];
    a0.x *= dn; a0.y *= dn; a0.z *= dn; a0.w *= dn;
    a1.x *= dn; a1.y *= dn; a1.z *= dn; a1.w *= dn;
    ((float4*)H)[(size_t)row * (M / 4) + c0 / 4] = a0;
    ((float4*)H)[(size_t)row * (M / 4) + c0 / 4 + 1] = a1;
}

// ---- fused aggregate over pre-scaled h': one WAVE per node, pure float4 adds.
// out[i] = dis[i]*(sum_{e} h'[src] + h'[i]) + b
template <int M, bool RELU>
__global__ void k_aggregate(const float* __restrict__ h, const float* __restrict__ dis,
                            const int* __restrict__ row_start, const int* __restrict__ csr_src,
                            const float* __restrict__ b, float* __restrict__ out, int n) {
    constexpr int G = M / 4;   // float4 groups per node row
    constexpr int S = 64 / G;  // edge slots per wave
    int gtid = blockIdx.x * blockDim.x + threadIdx.x;
    int node = gtid >> 6;
    if (node >= n) return;
    int lane = threadIdx.x & 63;
    int fg = lane % G;
    int slot = lane / G;
    int e1 = row_start[node + 1];
    const float4* h4 = (const float4*)h;
    float4 acc = make_float4(0.f, 0.f, 0.f, 0.f);
    int e = row_start[node] + slot;
    for (; e + S < e1; e += 2 * S) {
        int s0 = csr_src[e];
        int s1 = csr_src[e + S];
        float4 v0 = h4[(size_t)s0 * G + fg];
        float4 v1 = h4[(size_t)s1 * G + fg];
        acc.x += v0.x + v1.x;
        acc.y += v0.y + v1.y;
        acc.z += v0.z + v1.z;
        acc.w += v0.w + v1.w;
    }
    if (e < e1) {
        int s0 = csr_src[e];
        float4 v0 = h4[(size_t)s0 * G + fg];
        acc.x += v0.x;
        acc.y += v0.y;
        acc.z += v0.z;
        acc.w += v0.w;
    }
#pragma unroll
    for (int off = G; off < 64; off <<= 1) {
        acc.x += __shfl_xor(acc.x, off, 64);
        acc.y += __shfl_xor(acc.y, off, 64);
        acc.z += __shfl_xor(acc.z, off, 64);
        acc.w += __shfl_xor(acc.w, off, 64);
    }
    if (slot == 0) {
        float dn = dis[node];
        float4 hv = h4[(size_t)node * G + fg];
        float4 bb = ((const float4*)b)[fg];
        float4 r;
        r.x = (acc.x + hv.x) * dn + bb.x;
        r.y = (acc.y + hv.y) * dn + bb.y;
        r.z = (acc.z + hv.z) * dn + bb.z;
        r.w = (acc.w + hv.w) * dn + bb.w;
        if (RELU) {
            r.x = fmaxf(r.x, 0.f);
            r.y = fmaxf(r.y, 0.f);
            r.z = fmaxf(r.z, 0.f);
            r.w = fmaxf(r.w, 0.f);
        }
        ((float4*)out)[(size_t)node * G + fg] = r;
    }
}

extern "C" void kernel_launch(void* const* d_in, const int* in_sizes, int n_in,
                              void* d_out, int out_size, void* d_ws, size_t ws_size,
                              hipStream_t stream) {
    const float* x   = (const float*)d_in[0];
    const int*   ei  = (const int*)d_in[1];
    const float* W1  = (const float*)d_in[2];
    const float* b1  = (const float*)d_in[3];
    const float* W2  = (const float*)d_in[4];
    const float* b2  = (const float*)d_in[5];
    const float* W3  = (const float*)d_in[6];
    const float* b3  = (const float*)d_in[7];
    float* out = (float*)d_out;

    const int N = in_sizes[0] / 64;
    const int E = in_sizes[1] / 2;
    const int* src = ei;
    const int* dst = ei + E;

    const int NBK = cdiv(N, 256);     // 391 buckets of 256 nodes
    const int NBA = cdiv(E, ACHUNK);  // 391 pass-A blocks
    const int nmat = NBK * NBA;       // 152881 scan elements

    // workspace layout
    const size_t Np = (size_t)((N + 63) / 64) * 64;
    char* p = (char*)d_ws;
    int*      counts_t = (int*)p;      p += (size_t)nmat * sizeof(int);
    int*      offsets  = (int*)p;      p += (size_t)nmat * sizeof(int);
    int*      bsum     = (int*)p;      p += 1024 * sizeof(int);
    int*      row_start= (int*)p;      p += (Np + 64) * sizeof(int);
    float*    dis      = (float*)p;    p += Np * sizeof(float);
    unsigned* bucketed = (unsigned*)p; p += (size_t)E * sizeof(unsigned);
    int*      csr_src  = (int*)p;      p += (size_t)E * sizeof(int);
    float*    bufH     = (float*)p;    p += Np * 64 * sizeof(float);
    float*    bufX     = (float*)p;    p += Np * 64 * sizeof(float);
    (void)ws_size;

    const int B = 256;
    const int nb = cdiv(nmat, SCAN_CHUNK);  // 150

    // ---- CSR build: LDS counting sort, no global atomics ----
    k_bucket_hist<<<NBA, B, 0, stream>>>(dst, counts_t, NBK, NBA, E);
    k_scan_partial<<<nb, B, 0, stream>>>(counts_t, bsum, nmat);
    k_scan_bsum<<<1, 1024, 0, stream>>>(bsum, nb);
    k_scan_final<<<nb, B, 0, stream>>>(counts_t, bsum, offsets, nmat);
    k_bucket_scatter<<<NBA, B, 0, stream>>>(src, dst, offsets, bucketed, NBK, NBA, E);
    k_bucket_build<<<NBK, B, 0, stream>>>(bucketed, offsets, csr_src, row_start, dis,
                                          NBK, NBA, N, E);

    // ---- layer 1: x(64) -> 64, relu ----
    k_gemm<64, 64><<<cdiv(N, 32), B, 0, stream>>>(x, W1, dis, bufH, N);
    k_aggregate<64, true><<<cdiv(N * 64, B), B, 0, stream>>>(
        bufH, dis, row_start, csr_src, b1, bufX, N);

    // ---- layer 2: 64 -> 64, relu ----
    k_gemm<64, 64><<<cdiv(N, 32), B, 0, stream>>>(bufX, W2, dis, bufH, N);
    k_aggregate<64, true><<<cdiv(N * 64, B), B, 0, stream>>>(
        bufH, dis, row_start, csr_src, b2, bufX, N);

    // ---- layer 3: 64 -> 32, no relu ----
    k_gemm<64, 32><<<cdiv(N, 64), B, 0, stream>>>(bufX, W3, dis, bufH, N);
    k_aggregate<32, false><<<cdiv(N * 64, B), B, 0, stream>>>(
        bufH, dis, row_start, csr_src, b3, out, N);
}

// Round 7
// 335.429 us; speedup vs baseline: 1.2427x; 1.1921x over previous
//
#include <hip/hip_runtime.h>

// GCN: 3 layers, dims 64->64->64->32, N=100000 nodes, E=1600000 edges.
// Round 7: fp16 gather buffer. R6 evidence: k_aggregate is gather-BW-bound
// (FETCH 271MB of 410MB logical @ 3.8TB/s = 80us). Halve bytes/edge by
// storing h' as _Float16 (gemm epilogue converts; aggregate converts back
// and accumulates fp32). fp16 (not bf16): 10 mantissa bits keeps absmax
// under the 1.55e-2 threshold.
// CSR build: R6's LDS two-level counting sort (zero global atomics).
// dis[src] folded into h' at GEMM epilogue; aggregate inner loop = pure adds.

typedef __attribute__((ext_vector_type(8))) _Float16 half8;

static inline int cdiv(int a, int b) { return (a + b - 1) / b; }

#define ACHUNK 4096   // edges per pass-A block (256 thr x 16)
#define MAXNBK 512    // max buckets (N <= 131072)

// ---- pass A1: per-block bucket histogram -> counts_t[bucket*NBA + block]
__global__ void k_bucket_hist(const int* __restrict__ dst, int* __restrict__ counts_t,
                              int NBK, int NBA, int E) {
    __shared__ int cnt[MAXNBK];
    int t = threadIdx.x, b = blockIdx.x;
    for (int i = t; i < NBK; i += 256) cnt[i] = 0;
    __syncthreads();
    int e0 = b * ACHUNK;
#pragma unroll
    for (int j = 0; j < ACHUNK / 256; ++j) {
        int e = e0 + j * 256 + t;
        if (e < E) atomicAdd(&cnt[dst[e] >> 8], 1);
    }
    __syncthreads();
    for (int i = t; i < NBK; i += 256) counts_t[i * NBA + b] = cnt[i];
}

// ---- hierarchical exclusive scan over plain int array a[0..n) -> out[0..n)
#define SCAN_T 256
#define SCAN_V 4
#define SCAN_CHUNK 1024

__global__ void k_scan_partial(const int* __restrict__ a, int* __restrict__ bsum, int n) {
    __shared__ int red[SCAN_T];
    int t = threadIdx.x, b = blockIdx.x;
    int base = b * SCAN_CHUNK + t * SCAN_V;
    int s = 0;
#pragma unroll
    for (int j = 0; j < SCAN_V; ++j) { int i = base + j; if (i < n) s += a[i]; }
    red[t] = s;
    __syncthreads();
    for (int off = SCAN_T / 2; off > 0; off >>= 1) {
        if (t < off) red[t] += red[t + off];
        __syncthreads();
    }
    if (t == 0) bsum[b] = red[0];
}

__global__ void k_scan_bsum(int* bsum, int nb) {
    __shared__ int sh[1024];
    int t = threadIdx.x;
    int v = (t < nb) ? bsum[t] : 0;
    sh[t] = v;
    __syncthreads();
    for (int off = 1; off < 1024; off <<= 1) {
        int u = (t >= off) ? sh[t - off] : 0;
        __syncthreads();
        sh[t] += u;
        __syncthreads();
    }
    if (t < nb) bsum[t] = sh[t] - v;  // exclusive
}

__global__ void k_scan_final(const int* __restrict__ a, const int* __restrict__ bsum,
                             int* __restrict__ out, int n) {
    __shared__ int sh[SCAN_T];
    int t = threadIdx.x, b = blockIdx.x;
    int base = b * SCAN_CHUNK + t * SCAN_V;
    int v[SCAN_V];
    int s = 0;
#pragma unroll
    for (int j = 0; j < SCAN_V; ++j) {
        int i = base + j;
        v[j] = (i < n) ? a[i] : 0;
        s += v[j];
    }
    sh[t] = s;
    __syncthreads();
    for (int off = 1; off < SCAN_T; off <<= 1) {
        int u = (t >= off) ? sh[t - off] : 0;
        __syncthreads();
        sh[t] += u;
        __syncthreads();
    }
    int run = sh[t] - s + bsum[b];
#pragma unroll
    for (int j = 0; j < SCAN_V; ++j) {
        int i = base + j;
        if (i < n) { out[i] = run; run += v[j]; }
    }
}

// ---- pass A3: scatter edges into bucket regions via LDS cursors.
// packed word: src (24 bits) | (dst & 255) << 24. src < 2^17 fits.
__global__ void k_bucket_scatter(const int* __restrict__ src, const int* __restrict__ dst,
                                 const int* __restrict__ offsets, unsigned* __restrict__ bucketed,
                                 int NBK, int NBA, int E) {
    __shared__ int curs[MAXNBK];
    int t = threadIdx.x, b = blockIdx.x;
    for (int i = t; i < NBK; i += 256) curs[i] = offsets[i * NBA + b];
    __syncthreads();
    int e0 = b * ACHUNK;
#pragma unroll
    for (int j = 0; j < ACHUNK / 256; ++j) {
        int e = e0 + j * 256 + t;
        if (e < E) {
            int d = dst[e];
            int pos = atomicAdd(&curs[d >> 8], 1);
            bucketed[pos] = (unsigned)src[e] | ((unsigned)(d & 255) << 24);
        }
    }
}

// ---- pass B: one block per bucket. LDS hist over 256 nodes -> LDS scan ->
// emit csr_src (dst-sorted), row_start, dis.
__global__ void k_bucket_build(const unsigned* __restrict__ bucketed,
                               const int* __restrict__ offsets,
                               int* __restrict__ csr_src, int* __restrict__ row_start,
                               float* __restrict__ dis, int NBK, int NBA, int N, int E) {
    __shared__ int cnt[256];
    __shared__ int sc[256];
    int t = threadIdx.x, k = blockIdx.x;
    int base = offsets[k * NBA];
    int end = (k + 1 < NBK) ? offsets[(k + 1) * NBA] : E;
    cnt[t] = 0;
    __syncthreads();
    for (int i = base + t; i < end; i += 256)
        atomicAdd(&cnt[bucketed[i] >> 24], 1);
    __syncthreads();
    int c = cnt[t];
    sc[t] = c;
    __syncthreads();
    for (int off = 1; off < 256; off <<= 1) {
        int u = (t >= off) ? sc[t - off] : 0;
        __syncthreads();
        sc[t] += u;
        __syncthreads();
    }
    int excl = sc[t] - c;
    int node = k * 256 + t;
    if (node < N) {
        row_start[node] = base + excl;
        dis[node] = rsqrtf(1.0f + (float)c);
    }
    if (k == 0 && t == 0) row_start[N] = E;
    cnt[t] = base + excl;  // reuse as cursor
    __syncthreads();
    for (int i = base + t; i < end; i += 256) {
        unsigned w = bucketed[i];
        int pos = atomicAdd(&cnt[w >> 24], 1);
        csr_src[pos] = (int)(w & 0xFFFFFFu);
    }
}

// ---- H[n x M] = fp16( (X[n x K] @ W[K x M]) * dis[row] ); 8 outputs/thread.
template <int K, int M>
__global__ void k_gemm(const float* __restrict__ X, const float* __restrict__ W,
                       const float* __restrict__ dis, _Float16* __restrict__ H, int n) {
    constexpr int CPT = 8;
    constexpr int TPR = M / CPT;
    constexpr int ROWS = 256 / TPR;
    constexpr int KP = K + 1;
    __shared__ float Ws[K * M];
    __shared__ float Xs[ROWS * KP];
    int tid = threadIdx.x;
    for (int idx = tid; idx < K * M / 4; idx += 256)
        ((float4*)Ws)[idx] = ((const float4*)W)[idx];
    int row0 = blockIdx.x * ROWS;
    for (int idx = tid; idx < ROWS * (K / 4); idx += 256) {
        int r = idx / (K / 4), kq = idx % (K / 4);
        int row = row0 + r;
        float4 vv = (row < n) ? ((const float4*)X)[(size_t)row * (K / 4) + kq]
                              : make_float4(0.f, 0.f, 0.f, 0.f);
        Xs[r * KP + kq * 4 + 0] = vv.x;
        Xs[r * KP + kq * 4 + 1] = vv.y;
        Xs[r * KP + kq * 4 + 2] = vv.z;
        Xs[r * KP + kq * 4 + 3] = vv.w;
    }
    __syncthreads();
    int r = tid / TPR, c0 = (tid % TPR) * CPT;
    int row = row0 + r;
    if (row >= n) return;
    float4 a0 = make_float4(0.f, 0.f, 0.f, 0.f);
    float4 a1 = make_float4(0.f, 0.f, 0.f, 0.f);
#pragma unroll
    for (int k = 0; k < K; ++k) {
        float xv = Xs[r * KP + k];
        float4 w0 = ((const float4*)Ws)[(k * M + c0) / 4];
        float4 w1 = ((const float4*)Ws)[(k * M + c0) / 4 + 1];
        a0.x = fmaf(xv, w0.x, a0.x);
        a0.y = fmaf(xv, w0.y, a0.y);
        a0.z = fmaf(xv, w0.z, a0.z);
        a0.w = fmaf(xv, w0.w, a0.w);
        a1.x = fmaf(xv, w1.x, a1.x);
        a1.y = fmaf(xv, w1.y, a1.y);
        a1.z = fmaf(xv, w1.z, a1.z);
        a1.w = fmaf(xv, w1.w, a1.w);
    }
    float dn = dis[row];
    half8 hv;
    hv[0] = (_Float16)(a0.x * dn);
    hv[1] = (_Float16)(a0.y * dn);
    hv[2] = (_Float16)(a0.z * dn);
    hv[3] = (_Float16)(a0.w * dn);
    hv[4] = (_Float16)(a1.x * dn);
    hv[5] = (_Float16)(a1.y * dn);
    hv[6] = (_Float16)(a1.z * dn);
    hv[7] = (_Float16)(a1.w * dn);
    ((half8*)H)[(size_t)row * (M / CPT) + c0 / CPT] = hv;
}

// ---- fused aggregate over pre-scaled fp16 h': one WAVE per node.
// out[i] = dis[i]*(sum_{e} h'[src] + h'[i]) + b   (fp32 accumulation)
template <int M, bool RELU>
__global__ void k_aggregate(const _Float16* __restrict__ h, const float* __restrict__ dis,
                            const int* __restrict__ row_start, const int* __restrict__ csr_src,
                            const float* __restrict__ b, float* __restrict__ out, int n) {
    constexpr int G = M / 8;   // half8 groups per node row (8 for M=64, 4 for M=32)
    constexpr int S = 64 / G;  // edge slots per wave
    int gtid = blockIdx.x * blockDim.x + threadIdx.x;
    int node = gtid >> 6;
    if (node >= n) return;
    int lane = threadIdx.x & 63;
    int fg = lane % G;
    int slot = lane / G;
    int e1 = row_start[node + 1];
    const half8* h8 = (const half8*)h;
    float acc[8];
#pragma unroll
    for (int j = 0; j < 8; ++j) acc[j] = 0.f;
    int e = row_start[node] + slot;
    for (; e + S < e1; e += 2 * S) {
        int s0 = csr_src[e];
        int s1 = csr_src[e + S];
        half8 v0 = h8[(size_t)s0 * G + fg];
        half8 v1 = h8[(size_t)s1 * G + fg];
#pragma unroll
        for (int j = 0; j < 8; ++j) acc[j] += (float)v0[j] + (float)v1[j];
    }
    if (e < e1) {
        int s0 = csr_src[e];
        half8 v0 = h8[(size_t)s0 * G + fg];
#pragma unroll
        for (int j = 0; j < 8; ++j) acc[j] += (float)v0[j];
    }
#pragma unroll
    for (int off = G; off < 64; off <<= 1) {
#pragma unroll
        for (int j = 0; j < 8; ++j) acc[j] += __shfl_xor(acc[j], off, 64);
    }
    if (slot == 0) {
        float dn = dis[node];
        half8 hv = h8[(size_t)node * G + fg];
        const float* bp = b + fg * 8;
        float r[8];
#pragma unroll
        for (int j = 0; j < 8; ++j) {
            r[j] = (acc[j] + (float)hv[j]) * dn + bp[j];
            if (RELU) r[j] = fmaxf(r[j], 0.f);
        }
        float4* op = (float4*)(out + (size_t)node * M + fg * 8);
        op[0] = make_float4(r[0], r[1], r[2], r[3]);
        op[1] = make_float4(r[4], r[5], r[6], r[7]);
    }
}

extern "C" void kernel_launch(void* const* d_in, const int* in_sizes, int n_in,
                              void* d_out, int out_size, void* d_ws, size_t ws_size,
                              hipStream_t stream) {
    const float* x   = (const float*)d_in[0];
    const int*   ei  = (const int*)d_in[1];
    const float* W1  = (const float*)d_in[2];
    const float* b1  = (const float*)d_in[3];
    const float* W2  = (const float*)d_in[4];
    const float* b2  = (const float*)d_in[5];
    const float* W3  = (const float*)d_in[6];
    const float* b3  = (const float*)d_in[7];
    float* out = (float*)d_out;

    const int N = in_sizes[0] / 64;
    const int E = in_sizes[1] / 2;
    const int* src = ei;
    const int* dst = ei + E;

    const int NBK = cdiv(N, 256);     // 391 buckets of 256 nodes
    const int NBA = cdiv(E, ACHUNK);  // 391 pass-A blocks
    const int nmat = NBK * NBA;       // 152881 scan elements

    // workspace layout
    const size_t Np = (size_t)((N + 63) / 64) * 64;
    char* p = (char*)d_ws;
    int*      counts_t = (int*)p;      p += (size_t)nmat * sizeof(int);
    int*      offsets  = (int*)p;      p += (size_t)nmat * sizeof(int);
    int*      bsum     = (int*)p;      p += 1024 * sizeof(int);
    int*      row_start= (int*)p;      p += (Np + 64) * sizeof(int);
    float*    dis      = (float*)p;    p += Np * sizeof(float);
    unsigned* bucketed = (unsigned*)p; p += (size_t)E * sizeof(unsigned);
    int*      csr_src  = (int*)p;      p += (size_t)E * sizeof(int);
    _Float16* bufH     = (_Float16*)p; p += Np * 64 * sizeof(_Float16);
    float*    bufX     = (float*)p;    p += Np * 64 * sizeof(float);
    (void)ws_size;

    const int B = 256;
    const int nb = cdiv(nmat, SCAN_CHUNK);

    // ---- CSR build: LDS counting sort, no global atomics ----
    k_bucket_hist<<<NBA, B, 0, stream>>>(dst, counts_t, NBK, NBA, E);
    k_scan_partial<<<nb, B, 0, stream>>>(counts_t, bsum, nmat);
    k_scan_bsum<<<1, 1024, 0, stream>>>(bsum, nb);
    k_scan_final<<<nb, B, 0, stream>>>(counts_t, bsum, offsets, nmat);
    k_bucket_scatter<<<NBA, B, 0, stream>>>(src, dst, offsets, bucketed, NBK, NBA, E);
    k_bucket_build<<<NBK, B, 0, stream>>>(bucketed, offsets, csr_src, row_start, dis,
                                          NBK, NBA, N, E);

    // ---- layer 1: x(64) -> 64, relu ----
    k_gemm<64, 64><<<cdiv(N, 32), B, 0, stream>>>(x, W1, dis, bufH, N);
    k_aggregate<64, true><<<cdiv(N * 64, B), B, 0, stream>>>(
        bufH, dis, row_start, csr_src, b1, bufX, N);

    // ---- layer 2: 64 -> 64, relu ----
    k_gemm<64, 64><<<cdiv(N, 32), B, 0, stream>>>(bufX, W2, dis, bufH, N);
    k_aggregate<64, true><<<cdiv(N * 64, B), B, 0, stream>>>(
        bufH, dis, row_start, csr_src, b2, bufX, N);

    // ---- layer 3: 64 -> 32, no relu ----
    k_gemm<64, 32><<<cdiv(N, 64), B, 0, stream>>>(bufX, W3, dis, bufH, N);
    k_aggregate<32, false><<<cdiv(N * 64, B), B, 0, stream>>>(
        bufH, dis, row_start, csr_src, b3, out, N);
}